// Round 15
// baseline (140.522 us; speedup 1.0000x reference)
//
#include <hip/hip_runtime.h>
#include <hip/hip_fp16.h>
#include <math.h>

typedef unsigned short u16;
typedef _Float16 f16x8 __attribute__((ext_vector_type(8)));
typedef float f32x4 __attribute__((ext_vector_type(4)));
typedef u16 u16x8 __attribute__((ext_vector_type(8)));

#define B_ 4
#define L_ 2048
#define D_ 1024
#define H_ 16
#define DH 64
#define NF 1025
#define BH (B_*H_)

// ---- workspace layout (in floats) ----
#define Z_OFF    0
#define G_OFF    4194304
#define WSC_OFF  (G_OFF + 262144)
#define XB_OFF   (WSC_OFF + 4096)
#define PART_OFF (XB_OFF + 4096)
#define H1_OFF   (PART_OFF + 131072)
#define QP_OFF   (H1_OFF + 16384)
#define XHI_OFF  (QP_OFF + 32768)
#define WVH_OFF  (XHI_OFF + 4194304)
#define WOH_OFF  (WVH_OFF + 524288)

__device__ __forceinline__ u16 f2h(float f) {
    __half h = __float2half(f);
    return *reinterpret_cast<u16*>(&h);
}
__device__ __forceinline__ float h2fu(unsigned u) {
    u16 v = (u16)u;
    __half h = *reinterpret_cast<__half*>(&v);
    return __half2float(h);
}

// ---------------- xbar partial + x->fp16 (fused) ----------------
__global__ void k_xbar1h(const float* __restrict__ x, float* __restrict__ part,
                         u16* __restrict__ xhi) {
    int t = threadIdx.x;
    int dblk = blockIdx.x, lc = blockIdx.y, b = blockIdx.z;
    int d = dblk*256 + t;
    size_t rowbase = (size_t)b*L_ + (size_t)lc*64;
    const float* px = x + rowbase*D_ + d;
    u16* ph = xhi + rowbase*D_ + d;
    float s = 0.f;
    #pragma unroll 4
    for (int l = 0; l < 64; ++l) {
        float v = px[(size_t)l*D_];
        s += v;
        ph[(size_t)l*D_] = f2h(v);
    }
    part[(size_t)(b*32 + lc)*D_ + d] = s;
}

__global__ void k_xbar2(const float* __restrict__ part, float* __restrict__ xbar) {
    int id = blockIdx.x*256 + threadIdx.x;
    int b = id >> 10, d = id & 1023;
    float s = 0.f;
    for (int c = 0; c < 32; ++c) s += part[(size_t)(b*32 + c)*D_ + d];
    xbar[id] = s * (1.0f/(float)L_);
}

// ---------------- q_mean stage 1 ----------------
__global__ void k_qmean1(const float* __restrict__ xbar, const float* __restrict__ Wq,
                         float* __restrict__ qpart) {
    int t = threadIdx.x;
    int dblk = blockIdx.x, b = blockIdx.y, kc = blockIdx.z;
    int d = dblk*256 + t;
    const float* xb = xbar + b*D_ + kc*128;
    const float* wq = Wq + (size_t)(kc*128)*D_ + d;
    float s = 0.f;
    #pragma unroll 8
    for (int k = 0; k < 128; ++k) s += xb[k] * wq[(size_t)k*D_];
    qpart[((size_t)kc*B_ + b)*D_ + d] = s;
}

// ---------------- gates part A ----------------
__global__ void k_gates_a(const float* __restrict__ qpart,
                          const float* __restrict__ g_ln_w, const float* __restrict__ g_ln_b,
                          const float* __restrict__ g_w1,  const float* __restrict__ g_b1,
                          const float* __restrict__ w_ln_w, const float* __restrict__ w_ln_b,
                          const float* __restrict__ w_w1,  const float* __restrict__ w_b1,
                          const float* __restrict__ w_w2,  const float* __restrict__ w_b2,
                          float* __restrict__ h1_out, float* __restrict__ wscale) {
    int bh = blockIdx.x;
    int b = bh >> 4, h = bh & 15;
    int t = threadIdx.x;
    __shared__ float qm[64], hg[64], wh[64], w1o[64];

    if (t < 64) {
        float s = 0.f;
        #pragma unroll
        for (int kc = 0; kc < 8; ++kc)
            s += qpart[((size_t)kc*B_ + b)*D_ + h*64 + t];
        qm[t] = s;
    }
    __syncthreads();

    float m = 0.f;
    #pragma unroll
    for (int k = 0; k < 64; ++k) m += qm[k];
    m *= (1.0f/64.0f);
    float var = 0.f;
    #pragma unroll
    for (int k = 0; k < 64; ++k) { float df = qm[k]-m; var += df*df; }
    var *= (1.0f/64.0f);
    float rs = rsqrtf(var + 1e-5f);
    if (t < 64) {
        float c = (qm[t]-m)*rs;
        hg[t] = c*g_ln_w[t] + g_ln_b[t];
        wh[t] = c*w_ln_w[t] + w_ln_b[t];
    }
    __syncthreads();

    {
        float acc = g_b1[t];
        #pragma unroll 16
        for (int k = 0; k < 64; ++k) acc += hg[k]*g_w1[k*256 + t];
        h1_out[bh*256 + t] = 0.5f*acc*(1.0f + erff(acc*0.70710678118654752f));
    }
    if (t < 64) {
        float acc = w_b1[t];
        #pragma unroll 16
        for (int k = 0; k < 64; ++k) acc += wh[k]*w_w1[k*64 + t];
        w1o[t] = 0.5f*acc*(1.0f + erff(acc*0.70710678118654752f));
    }
    __syncthreads();

    if (t < 64) {
        float acc = w_b2[t];
        #pragma unroll 16
        for (int k = 0; k < 64; ++k) acc += w1o[k]*w_w2[k*64 + t];
        wscale[bh*64 + t] = 1.0f + 1.0f/(1.0f + expf(-acc));
    }
}

// ---------------- gates part B v4 ----------------
__global__ __launch_bounds__(256) void k_gate_g(const float* __restrict__ h1_ws,
                                                const float* __restrict__ g_w2,
                                                const float* __restrict__ g_b2,
                                                const float* __restrict__ mod_bias,
                                                float* __restrict__ G) {
    int bh = blockIdx.y;
    int t = threadIdx.x;
    int w = t >> 6, l = t & 63;
    int f = blockIdx.x*64 + l;
    int fc = f < NF ? f : NF-1;
    __shared__ float h1s[256];
    __shared__ float rre[4][64], rim[4][64];
    h1s[t] = h1_ws[bh*256 + t];
    __syncthreads();

    float re = 0.f, im = 0.f;
    const float* gw = g_w2 + (size_t)(w*64)*2050;
    const float* h1p = h1s + w*64;
    #pragma unroll 8
    for (int k = 0; k < 64; ++k) {
        float hv = h1p[k];
        re += hv * gw[(size_t)k*2050 + fc];
        im += hv * gw[(size_t)k*2050 + NF + fc];
    }
    rre[w][l] = re; rim[w][l] = im;
    __syncthreads();
    if (w == 0 && f < NF) {
        float rr = rre[0][l]+rre[1][l]+rre[2][l]+rre[3][l] + g_b2[f];
        float ii = rim[0][l]+rim[1][l]+rim[2][l]+rim[3][l] + g_b2[NF+f];
        float mag = sqrtf(rr*rr + ii*ii);
        float mult = fmaxf(mag + mod_bias[f], 0.f) / (mag + 1e-6f);
        float s = mult * (1.0f/2048.0f);
        float gr = s*rr, gi = s*ii;
        if (f == 0 || f == 1024) gi = 0.f;
        float* Gb = G + (size_t)bh*4096;
        Gb[2*f]   = gr;
        Gb[2*f+1] = gi;
        if (f >= 1 && f <= 1023) {
            Gb[2*(2048-f)]   = gr;
            Gb[2*(2048-f)+1] = -gi;
        }
    }
}

// ---------------- weight transpose + fp16 convert ----------------
__global__ void k_wsplit(const float* __restrict__ Wv, const float* __restrict__ Wo,
                         u16* __restrict__ WvH, u16* __restrict__ WoH) {
    const float* W = blockIdx.z ? Wo : Wv;
    u16* TH = blockIdx.z ? WoH : WvH;
    __shared__ float tile[32][33];
    int t = threadIdx.x;
    int n0 = blockIdx.x*32, k0 = blockIdx.y*32;
    #pragma unroll
    for (int i = 0; i < 4; ++i) {
        int k = (t >> 5) + 8*i;
        tile[k][t & 31] = W[(size_t)(k0 + k)*D_ + n0 + (t & 31)];
    }
    __syncthreads();
    int n = t >> 3, kc = (t & 7)*4;
    ushort4 h;
    h.x = f2h(tile[kc+0][n]);
    h.y = f2h(tile[kc+1][n]);
    h.z = f2h(tile[kc+2][n]);
    h.w = f2h(tile[kc+3][n]);
    *(ushort4*)&TH[(size_t)(n0 + n)*D_ + k0 + kc] = h;
}

// ======== GEMM1 "pipe": 64x128, BK=64, dbuf + sched_barrier issue-pin + setprio ========
__device__ __forceinline__ void p_stageA(const u16* __restrict__ Ag, size_t rowBase, int k0,
                                         u16* As, int t) {
    #pragma unroll
    for (int i = 0; i < 2; ++i) {
        int c = t + i*256;
        int r = c >> 3, cs = c & 7;
        int ko = (cs ^ (r & 7)) << 3;
        __builtin_amdgcn_global_load_lds(
            (const __attribute__((address_space(1))) void*)(Ag + (rowBase + (size_t)r)*D_ + k0 + ko),
            (__attribute__((address_space(3))) void*)(As + c*8), 16, 0, 0);
    }
}
__device__ __forceinline__ void p_stageB(const u16* __restrict__ Bg, int colBase, int k0,
                                         u16* Bs, int t) {
    #pragma unroll
    for (int i = 0; i < 4; ++i) {
        int c = t + i*256;
        int r = c >> 3, cs = c & 7;
        int ko = (cs ^ (r & 7)) << 3;
        __builtin_amdgcn_global_load_lds(
            (const __attribute__((address_space(1))) void*)(Bg + ((size_t)colBase + r)*D_ + k0 + ko),
            (__attribute__((address_space(3))) void*)(Bs + c*8), 16, 0, 0);
    }
}

__global__ __launch_bounds__(256) void k_gemm_pipe(const u16* __restrict__ Ahi,
                                                   const u16* __restrict__ Bhi,
                                                   float* __restrict__ C) {
    __shared__ u16 As[2][64*64], Bs[2][128*64];   // 48 KiB
    int t = threadIdx.x;
    size_t rowBase = (size_t)blockIdx.x * 64;
    int colBase = blockIdx.y * 128;
    f32x4 acc[2][4] = {};
    int lane = t & 63;
    int wr = (t >> 7) & 1, wc = (t >> 6) & 1;
    int lr = lane & 15, lq = lane >> 4;

    p_stageA(Ahi, rowBase, 0, As[0], t);
    p_stageB(Bhi, colBase, 0, Bs[0], t);
    __syncthreads();

    int cur = 0;
    for (int step = 0; step < 16; ++step) {
        if (step < 15) {
            p_stageA(Ahi, rowBase, (step+1)*64, As[cur^1], t);
            p_stageB(Bhi, colBase, (step+1)*64, Bs[cur^1], t);
        }
        // Pin: next-tile load issues must not be sunk below the compute.
        __builtin_amdgcn_sched_barrier(0);
        __builtin_amdgcn_s_setprio(1);
        #pragma unroll
        for (int ks = 0; ks < 2; ++ks) {
            f16x8 ah[2], bh[4];
            #pragma unroll
            for (int m = 0; m < 2; ++m) {
                int row = wr*32 + m*16 + lr;
                int ch = (ks*4 + lq) ^ (row & 7);
                ah[m] = *(const f16x8*)(As[cur] + row*64 + ch*8);
            }
            #pragma unroll
            for (int n = 0; n < 4; ++n) {
                int row = wc*64 + n*16 + lr;
                int ch = (ks*4 + lq) ^ (row & 7);
                bh[n] = *(const f16x8*)(Bs[cur] + row*64 + ch*8);
            }
            #pragma unroll
            for (int m = 0; m < 2; ++m) {
                #pragma unroll
                for (int n = 0; n < 4; ++n) {
                    acc[m][n] = __builtin_amdgcn_mfma_f32_16x16x32_f16(ah[m], bh[n], acc[m][n], 0, 0, 0);
                }
            }
        }
        __builtin_amdgcn_s_setprio(0);
        __syncthreads();   // drains vmcnt(0)+lgkmcnt(0): next tile fully in LDS
        cur ^= 1;
    }

    int cr = lq * 4, cc = lane & 15;
    u16* Z = (u16*)C;
    #pragma unroll
    for (int m = 0; m < 2; ++m) {
        #pragma unroll
        for (int n = 0; n < 4; ++n) {
            int d = colBase + wc*64 + n*16 + cc;
            int hh = d >> 6, pr = (d >> 1) & 31, p = d & 1;
            #pragma unroll
            for (int r = 0; r < 4; ++r) {
                size_t gr = rowBase + wr*32 + m*16 + cr + r;
                int b = (int)(gr >> 11), l = (int)(gr & 2047);
                Z[(((size_t)((b*16 + hh)*32 + pr))*L_ + l)*2 + p] = f2h(acc[m][n][r]);
            }
        }
    }
}

// ======== GEMM2 control: R12-proven plain 2-barrier 64x128, fp32 out ========
__global__ __launch_bounds__(256) void k_mfma_gemm(const u16* __restrict__ Ahi,
                                                   const u16* __restrict__ Bhi,
                                                   float* __restrict__ C) {
    __shared__ u16 AsH[64*64], BsH[128*64];   // 24 KiB
    int t = threadIdx.x;
    size_t rowBase = (size_t)blockIdx.x * 64;
    int colBase = blockIdx.y * 128;
    f32x4 acc[2][4] = {};
    int lane = t & 63;
    int wr = (t >> 7) & 1, wc = (t >> 6) & 1;
    int lr = lane & 15, lq = lane >> 4;

    for (int k0 = 0; k0 < 1024; k0 += 64) {
        #pragma unroll
        for (int i = 0; i < 2; ++i) {
            int c = t + i*256;
            int r = c >> 3, cs = c & 7;
            int ko = (cs ^ (r & 7)) << 3;
            __builtin_amdgcn_global_load_lds(
                (const __attribute__((address_space(1))) void*)(Ahi + (rowBase + (size_t)r)*D_ + k0 + ko),
                (__attribute__((address_space(3))) void*)(AsH + c*8), 16, 0, 0);
        }
        #pragma unroll
        for (int i = 0; i < 4; ++i) {
            int c = t + i*256;
            int r = c >> 3, cs = c & 7;
            int ko = (cs ^ (r & 7)) << 3;
            __builtin_amdgcn_global_load_lds(
                (const __attribute__((address_space(1))) void*)(Bhi + ((size_t)colBase + r)*D_ + k0 + ko),
                (__attribute__((address_space(3))) void*)(BsH + c*8), 16, 0, 0);
        }
        __syncthreads();
        #pragma unroll
        for (int ks = 0; ks < 2; ++ks) {
            f16x8 ah[2], bh[4];
            #pragma unroll
            for (int m = 0; m < 2; ++m) {
                int row = wr*32 + m*16 + lr;
                int ch = (ks*4 + lq) ^ (row & 7);
                ah[m] = *(const f16x8*)(AsH + row*64 + ch*8);
            }
            #pragma unroll
            for (int n = 0; n < 4; ++n) {
                int row = wc*64 + n*16 + lr;
                int ch = (ks*4 + lq) ^ (row & 7);
                bh[n] = *(const f16x8*)(BsH + row*64 + ch*8);
            }
            #pragma unroll
            for (int m = 0; m < 2; ++m) {
                #pragma unroll
                for (int n = 0; n < 4; ++n) {
                    acc[m][n] = __builtin_amdgcn_mfma_f32_16x16x32_f16(ah[m], bh[n], acc[m][n], 0, 0, 0);
                }
            }
        }
        __syncthreads();
    }

    int cr = lq * 4, cc = lane & 15;
    #pragma unroll
    for (int m = 0; m < 2; ++m) {
        #pragma unroll
        for (int n = 0; n < 4; ++n) {
            int d = colBase + wc*64 + n*16 + cc;
            #pragma unroll
            for (int r = 0; r < 4; ++r) {
                size_t gr = rowBase + wr*32 + m*16 + cr + r;
                C[gr*D_ + d] = acc[m][n][r];
            }
        }
    }
}

// ---------------- register radix-8 FFT-2048 (fp16 I/O, fp32 compute) ----------------
__device__ __forceinline__ float2 cmulp(float2 a, float2 b) {
    return make_float2(a.x*b.x - a.y*b.y, a.x*b.y + a.y*b.x);
}
__device__ __forceinline__ float2 cadd(float2 a, float2 b){ return make_float2(a.x+b.x, a.y+b.y); }
__device__ __forceinline__ float2 csub(float2 a, float2 b){ return make_float2(a.x-b.x, a.y-b.y); }
__device__ __forceinline__ float2 cnegi(float2 a){ return make_float2(a.y, -a.x); }
__device__ __forceinline__ float2 cposi(float2 a){ return make_float2(-a.y, a.x); }

#define RH_ 0.70710678118654752f

__device__ __forceinline__ void fwd3(float2* e, float2 w1) {
    float2 tA1 = make_float2((w1.x + w1.y)*RH_, (w1.y - w1.x)*RH_);
    float2 tA2 = cnegi(w1);
    float2 tA3 = make_float2((w1.y - w1.x)*RH_, -(w1.x + w1.y)*RH_);
    float2 a, b, d;
    a=e[0]; b=e[4]; e[0]=cadd(a,b); d=csub(a,b); e[4]=cmulp(d, w1);
    a=e[1]; b=e[5]; e[1]=cadd(a,b); d=csub(a,b); e[5]=cmulp(d, tA1);
    a=e[2]; b=e[6]; e[2]=cadd(a,b); d=csub(a,b); e[6]=cmulp(d, tA2);
    a=e[3]; b=e[7]; e[3]=cadd(a,b); d=csub(a,b); e[7]=cmulp(d, tA3);
    float2 w2 = cmulp(w1,w1); float2 w2n = cnegi(w2);
    a=e[0]; b=e[2]; e[0]=cadd(a,b); d=csub(a,b); e[2]=cmulp(d, w2);
    a=e[1]; b=e[3]; e[1]=cadd(a,b); d=csub(a,b); e[3]=cmulp(d, w2n);
    a=e[4]; b=e[6]; e[4]=cadd(a,b); d=csub(a,b); e[6]=cmulp(d, w2);
    a=e[5]; b=e[7]; e[5]=cadd(a,b); d=csub(a,b); e[7]=cmulp(d, w2n);
    float2 w4 = cmulp(w2,w2);
    a=e[0]; b=e[1]; e[0]=cadd(a,b); d=csub(a,b); e[1]=cmulp(d, w4);
    a=e[2]; b=e[3]; e[2]=cadd(a,b); d=csub(a,b); e[3]=cmulp(d, w4);
    a=e[4]; b=e[5]; e[4]=cadd(a,b); d=csub(a,b); e[5]=cmulp(d, w4);
    a=e[6]; b=e[7]; e[6]=cadd(a,b); d=csub(a,b); e[7]=cmulp(d, w4);
}

__device__ __forceinline__ void inv3(float2* e, float2 b1) {
    float2 b2 = cmulp(b1,b1), b4 = cmulp(b2,b2);
    float2 a, bb;
    bb=cmulp(e[1],b4); a=e[0]; e[0]=cadd(a,bb); e[1]=csub(a,bb);
    bb=cmulp(e[3],b4); a=e[2]; e[2]=cadd(a,bb); e[3]=csub(a,bb);
    bb=cmulp(e[5],b4); a=e[4]; e[4]=cadd(a,bb); e[5]=csub(a,bb);
    bb=cmulp(e[7],b4); a=e[6]; e[6]=cadd(a,bb); e[7]=csub(a,bb);
    float2 b2i = cposi(b2);
    bb=cmulp(e[2],b2);  a=e[0]; e[0]=cadd(a,bb); e[2]=csub(a,bb);
    bb=cmulp(e[3],b2i); a=e[1]; e[1]=cadd(a,bb); e[3]=csub(a,bb);
    bb=cmulp(e[6],b2);  a=e[4]; e[4]=cadd(a,bb); e[6]=csub(a,bb);
    bb=cmulp(e[7],b2i); a=e[5]; e[5]=cadd(a,bb); e[7]=csub(a,bb);
    float2 tB1 = make_float2((b1.x - b1.y)*RH_, (b1.x + b1.y)*RH_);
    float2 tB2 = cposi(b1);
    float2 tB3 = make_float2(-(b1.x + b1.y)*RH_, (b1.x - b1.y)*RH_);
    bb=cmulp(e[4],b1);  a=e[0]; e[0]=cadd(a,bb); e[4]=csub(a,bb);
    bb=cmulp(e[5],tB1); a=e[1]; e[1]=cadd(a,bb); e[5]=csub(a,bb);
    bb=cmulp(e[6],tB2); a=e[2]; e[2]=cadd(a,bb); e[6]=csub(a,bb);
    bb=cmulp(e[7],tB3); a=e[3]; e[3]=cadd(a,bb); e[7]=csub(a,bb);
}

__device__ __forceinline__ void inv2(float2* e, float2 b1) {
    float2 b2 = cmulp(b1,b1);
    float2 a, bb;
    bb=cmulp(e[1],b2); a=e[0]; e[0]=cadd(a,bb); e[1]=csub(a,bb);
    bb=cmulp(e[3],b2); a=e[2]; e[2]=cadd(a,bb); e[3]=csub(a,bb);
    float2 b1i = cposi(b1);
    bb=cmulp(e[2],b1);  a=e[0]; e[0]=cadd(a,bb); e[2]=csub(a,bb);
    bb=cmulp(e[3],b1i); a=e[1]; e[1]=cadd(a,bb); e[3]=csub(a,bb);
}

#define PIDX(i) ((i) + ((i)>>5))

__global__ __launch_bounds__(256, 4) void k_fft(unsigned* __restrict__ z16,
                                                const float* __restrict__ G,
                                                const float* __restrict__ wscale) {
    __shared__ float2 dsh[2112];
    int t = threadIdx.x;
    int row = blockIdx.x;
    int bh = row >> 5, jp = row & 31;
    unsigned* zr = z16 + (size_t)row * L_;
    const float PIO = 3.14159265358979323846f;

    float2 e[8];
    #pragma unroll
    for (int j = 0; j < 8; ++j) {
        unsigned u = zr[t + 256*j];
        e[j] = make_float2(h2fu(u & 0xffffu), h2fu(u >> 16));
    }
    {
        float s_, c_; __sincosf(-(PIO/1024.f)*(float)t, &s_, &c_);
        fwd3(e, make_float2(c_, s_));
    }
    #pragma unroll
    for (int j = 0; j < 8; ++j) { int i = t + 256*j; dsh[PIDX(i)] = e[j]; }
    __syncthreads();

    {
        int q = t >> 5, r = t & 31, base = q*256 + r;
        #pragma unroll
        for (int j = 0; j < 8; ++j) { int i = base + 32*j; e[j] = dsh[PIDX(i)]; }
        float s_, c_; __sincosf(-(PIO/128.f)*(float)r, &s_, &c_);
        fwd3(e, make_float2(c_, s_));
        #pragma unroll
        for (int j = 0; j < 8; ++j) { int i = base + 32*j; dsh[PIDX(i)] = e[j]; }
    }
    __syncthreads();

    {
        int q = t >> 2, r = t & 3, base = q*32 + r;
        #pragma unroll
        for (int j = 0; j < 8; ++j) { int i = base + 4*j; e[j] = dsh[PIDX(i)]; }
        float s_, c_; __sincosf(-(PIO/16.f)*(float)r, &s_, &c_);
        fwd3(e, make_float2(c_, s_));
        #pragma unroll
        for (int j = 0; j < 8; ++j) { int i = base + 4*j; dsh[PIDX(i)] = e[j]; }
    }
    __syncthreads();

    {
        #pragma unroll
        for (int u = 0; u < 8; ++u) { int i = 8*t + u; e[u] = dsh[PIDX(i)]; }
        float2 a, b, d;
        a=e[0]; b=e[2]; e[0]=cadd(a,b); e[2]=csub(a,b);
        a=e[1]; b=e[3]; e[1]=cadd(a,b); d=csub(a,b); e[3]=cnegi(d);
        a=e[4]; b=e[6]; e[4]=cadd(a,b); e[6]=csub(a,b);
        a=e[5]; b=e[7]; e[5]=cadd(a,b); d=csub(a,b); e[7]=cnegi(d);
        a=e[0]; b=e[1]; e[0]=cadd(a,b); e[1]=csub(a,b);
        a=e[2]; b=e[3]; e[2]=cadd(a,b); e[3]=csub(a,b);
        a=e[4]; b=e[5]; e[4]=cadd(a,b); e[5]=csub(a,b);
        a=e[6]; b=e[7]; e[6]=cadd(a,b); e[7]=csub(a,b);
        int flo = (int)(__brev((unsigned)t) >> 24);
        const float2* Gb = (const float2*)(G + (size_t)bh*4096);
        e[0] = cmulp(e[0], Gb[flo + 256*0]);
        e[1] = cmulp(e[1], Gb[flo + 256*4]);
        e[2] = cmulp(e[2], Gb[flo + 256*2]);
        e[3] = cmulp(e[3], Gb[flo + 256*6]);
        e[4] = cmulp(e[4], Gb[flo + 256*1]);
        e[5] = cmulp(e[5], Gb[flo + 256*5]);
        e[6] = cmulp(e[6], Gb[flo + 256*3]);
        e[7] = cmulp(e[7], Gb[flo + 256*7]);
        inv3(e, make_float2(1.f, 0.f));
        #pragma unroll
        for (int u = 0; u < 8; ++u) { int i = 8*t + u; dsh[PIDX(i)] = e[u]; }
    }
    __syncthreads();

    {
        int q = t >> 3, r = t & 7, base = q*64 + r;
        #pragma unroll
        for (int j = 0; j < 8; ++j) { int i = base + 8*j; e[j] = dsh[PIDX(i)]; }
        float s_, c_; __sincosf((PIO/32.f)*(float)r, &s_, &c_);
        inv3(e, make_float2(c_, s_));
        #pragma unroll
        for (int j = 0; j < 8; ++j) { int i = base + 8*j; dsh[PIDX(i)] = e[j]; }
    }
    __syncthreads();

    {
        int q = t >> 6, r = t & 63, base = q*512 + r;
        #pragma unroll
        for (int j = 0; j < 8; ++j) { int i = base + 64*j; e[j] = dsh[PIDX(i)]; }
        float s_, c_; __sincosf((PIO/256.f)*(float)r, &s_, &c_);
        inv3(e, make_float2(c_, s_));
        #pragma unroll
        for (int j = 0; j < 8; ++j) { int i = base + 64*j; dsh[PIDX(i)] = e[j]; }
    }
    __syncthreads();

    {
        #pragma unroll
        for (int j = 0; j < 4; ++j) { int i = t + 512*j; e[j] = dsh[PIDX(i)]; }
        #pragma unroll
        for (int j = 0; j < 4; ++j) { int i = t + 256 + 512*j; e[4+j] = dsh[PIDX(i)]; }
        float s_, c_; __sincosf((PIO/1024.f)*(float)t, &s_, &c_);
        float2 b1 = make_float2(c_, s_);
        inv2(e, b1);
        float2 b1b = make_float2((b1.x - b1.y)*RH_, (b1.x + b1.y)*RH_);
        inv2(e+4, b1b);
        float sc0 = wscale[bh*64 + 2*jp];
        float sc1 = wscale[bh*64 + 2*jp + 1];
        #pragma unroll
        for (int j = 0; j < 4; ++j) {
            unsigned lo = f2h(e[j].x*sc0), hi = f2h(e[j].y*sc1);
            zr[t + 512*j] = lo | (hi << 16);
        }
        #pragma unroll
        for (int j = 0; j < 4; ++j) {
            unsigned lo = f2h(e[4+j].x*sc0), hi = f2h(e[4+j].y*sc1);
            zr[t + 256 + 512*j] = lo | (hi << 16);
        }
    }
}

// ---------------- z16 (fp16 pairs) -> vmix [m][d] fp16 transpose ----------------
__global__ void k_vsplit(const unsigned* __restrict__ z16, u16* __restrict__ vhi) {
    int t = threadIdx.x;
    int lt = blockIdx.x, h = blockIdx.y, b = blockIdx.z;
    int l0 = lt*64;
    __shared__ unsigned tile[64][33];
    const unsigned* zb = z16 + (size_t)(b*16 + h)*32*L_;
    int pr = t >> 3, lg = t & 7;
    #pragma unroll
    for (int i = 0; i < 8; ++i) {
        int l = lg*8 + i;
        tile[l][pr] = zb[(size_t)pr*L_ + l0 + l];
    }
    __syncthreads();
    int l = t >> 2, q0 = (t & 3) * 8;
    u16x8 o0, o1;
    #pragma unroll
    for (int i = 0; i < 4; ++i) {
        unsigned u = tile[l][q0+i];
        o0[2*i]   = (u16)(u & 0xffffu);
        o0[2*i+1] = (u16)(u >> 16);
    }
    #pragma unroll
    for (int i = 0; i < 4; ++i) {
        unsigned u = tile[l][q0+4+i];
        o1[2*i]   = (u16)(u & 0xffffu);
        o1[2*i+1] = (u16)(u >> 16);
    }
    size_t base = ((size_t)(b*L_) + l0 + l)*D_ + h*64 + q0*2;
    *(u16x8*)&vhi[base]   = o0;
    *(u16x8*)&vhi[base+8] = o1;
}

extern "C" void kernel_launch(void* const* d_in, const int* in_sizes, int n_in,
                              void* d_out, int out_size, void* d_ws, size_t ws_size,
                              hipStream_t stream) {
    const float* x      = (const float*)d_in[0];
    const float* Wq     = (const float*)d_in[1];
    const float* Wv     = (const float*)d_in[2];
    const float* Wo     = (const float*)d_in[3];
    const float* g_ln_w = (const float*)d_in[4];
    const float* g_ln_b = (const float*)d_in[5];
    const float* g_w1   = (const float*)d_in[6];
    const float* g_b1   = (const float*)d_in[7];
    const float* g_w2   = (const float*)d_in[8];
    const float* g_b2   = (const float*)d_in[9];
    const float* mod_b  = (const float*)d_in[10];
    const float* w_ln_w = (const float*)d_in[11];
    const float* w_ln_b = (const float*)d_in[12];
    const float* w_w1   = (const float*)d_in[13];
    const float* w_b1   = (const float*)d_in[14];
    const float* w_w2   = (const float*)d_in[15];
    const float* w_b2   = (const float*)d_in[16];

    float* ws   = (float*)d_ws;
    unsigned* z16 = (unsigned*)(ws + Z_OFF);
    float* G    = ws + G_OFF;
    float* wsc  = ws + WSC_OFF;
    float* xbar = ws + XB_OFF;
    float* part = ws + PART_OFF;
    float* h1ws = ws + H1_OFF;
    float* qpart= ws + QP_OFF;
    u16* xhi = (u16*)(ws + XHI_OFF);
    u16* WvH = (u16*)(ws + WVH_OFF);
    u16* WoH = (u16*)(ws + WOH_OFF);
    u16* vhi = xhi;
    float* outp = (float*)d_out;

    dim3 gx(4, 32, 4);
    k_xbar1h<<<gx, 256, 0, stream>>>(x, part, xhi);
    k_xbar2<<<16, 256, 0, stream>>>(part, xbar);
    dim3 gq(4, 4, 8);
    k_qmean1<<<gq, 256, 0, stream>>>(xbar, Wq, qpart);
    k_gates_a<<<64, 256, 0, stream>>>(qpart, g_ln_w, g_ln_b, g_w1, g_b1,
                                      w_ln_w, w_ln_b, w_w1, w_b1, w_w2, w_b2,
                                      h1ws, wsc);
    dim3 ggate(17, 64);
    k_gate_g<<<ggate, 256, 0, stream>>>(h1ws, g_w2, g_b2, mod_b, G);
    dim3 gw(32, 32, 2);
    k_wsplit<<<gw, 256, 0, stream>>>(Wv, Wo, WvH, WoH);

    dim3 gg(128, 8);
    k_gemm_pipe<<<gg, 256, 0, stream>>>(xhi, WvH, (float*)z16);
    k_fft<<<2048, 256, 0, stream>>>(z16, G, wsc);
    dim3 gv(32, 16, 4);
    k_vsplit<<<gv, 256, 0, stream>>>(z16, vhi);
    k_mfma_gemm<<<gg, 256, 0, stream>>>(vhi, WoH, outp);
}

// Round 16
// 131.582 us; speedup vs baseline: 1.0679x; 1.0679x over previous
//
#include <hip/hip_runtime.h>
#include <hip/hip_fp16.h>
#include <math.h>

typedef unsigned short u16;
typedef _Float16 f16x8 __attribute__((ext_vector_type(8)));
typedef float f32x4 __attribute__((ext_vector_type(4)));
typedef u16 u16x8 __attribute__((ext_vector_type(8)));

#define B_ 4
#define L_ 2048
#define D_ 1024
#define H_ 16
#define DH 64
#define NF 1025
#define BH (B_*H_)

// ---- workspace layout (in floats) ----
#define Z_OFF    0
#define G_OFF    4194304
#define WSC_OFF  (G_OFF + 262144)
#define XB_OFF   (WSC_OFF + 4096)
#define PART_OFF (XB_OFF + 4096)
#define H1_OFF   (PART_OFF + 131072)
#define QP_OFF   (H1_OFF + 16384)
#define XHI_OFF  (QP_OFF + 32768)
#define WVH_OFF  (XHI_OFF + 4194304)
#define WOH_OFF  (WVH_OFF + 524288)

__device__ __forceinline__ u16 f2h(float f) {
    __half h = __float2half(f);
    return *reinterpret_cast<u16*>(&h);
}
__device__ __forceinline__ float h2fu(unsigned u) {
    u16 v = (u16)u;
    __half h = *reinterpret_cast<__half*>(&v);
    return __half2float(h);
}

// ---------------- xbar partial + x->fp16 (fused) ----------------
__global__ void k_xbar1h(const float* __restrict__ x, float* __restrict__ part,
                         u16* __restrict__ xhi) {
    int t = threadIdx.x;
    int dblk = blockIdx.x, lc = blockIdx.y, b = blockIdx.z;
    int d = dblk*256 + t;
    size_t rowbase = (size_t)b*L_ + (size_t)lc*64;
    const float* px = x + rowbase*D_ + d;
    u16* ph = xhi + rowbase*D_ + d;
    float s = 0.f;
    #pragma unroll 4
    for (int l = 0; l < 64; ++l) {
        float v = px[(size_t)l*D_];
        s += v;
        ph[(size_t)l*D_] = f2h(v);
    }
    part[(size_t)(b*32 + lc)*D_ + d] = s;
}

__global__ void k_xbar2(const float* __restrict__ part, float* __restrict__ xbar) {
    int id = blockIdx.x*256 + threadIdx.x;
    int b = id >> 10, d = id & 1023;
    float s = 0.f;
    for (int c = 0; c < 32; ++c) s += part[(size_t)(b*32 + c)*D_ + d];
    xbar[id] = s * (1.0f/(float)L_);
}

// ---------------- q_mean stage 1 ----------------
__global__ void k_qmean1(const float* __restrict__ xbar, const float* __restrict__ Wq,
                         float* __restrict__ qpart) {
    int t = threadIdx.x;
    int dblk = blockIdx.x, b = blockIdx.y, kc = blockIdx.z;
    int d = dblk*256 + t;
    const float* xb = xbar + b*D_ + kc*128;
    const float* wq = Wq + (size_t)(kc*128)*D_ + d;
    float s = 0.f;
    #pragma unroll 8
    for (int k = 0; k < 128; ++k) s += xb[k] * wq[(size_t)k*D_];
    qpart[((size_t)kc*B_ + b)*D_ + d] = s;
}

// ---------------- gates part A ----------------
__global__ void k_gates_a(const float* __restrict__ qpart,
                          const float* __restrict__ g_ln_w, const float* __restrict__ g_ln_b,
                          const float* __restrict__ g_w1,  const float* __restrict__ g_b1,
                          const float* __restrict__ w_ln_w, const float* __restrict__ w_ln_b,
                          const float* __restrict__ w_w1,  const float* __restrict__ w_b1,
                          const float* __restrict__ w_w2,  const float* __restrict__ w_b2,
                          float* __restrict__ h1_out, float* __restrict__ wscale) {
    int bh = blockIdx.x;
    int b = bh >> 4, h = bh & 15;
    int t = threadIdx.x;
    __shared__ float qm[64], hg[64], wh[64], w1o[64];

    if (t < 64) {
        float s = 0.f;
        #pragma unroll
        for (int kc = 0; kc < 8; ++kc)
            s += qpart[((size_t)kc*B_ + b)*D_ + h*64 + t];
        qm[t] = s;
    }
    __syncthreads();

    float m = 0.f;
    #pragma unroll
    for (int k = 0; k < 64; ++k) m += qm[k];
    m *= (1.0f/64.0f);
    float var = 0.f;
    #pragma unroll
    for (int k = 0; k < 64; ++k) { float df = qm[k]-m; var += df*df; }
    var *= (1.0f/64.0f);
    float rs = rsqrtf(var + 1e-5f);
    if (t < 64) {
        float c = (qm[t]-m)*rs;
        hg[t] = c*g_ln_w[t] + g_ln_b[t];
        wh[t] = c*w_ln_w[t] + w_ln_b[t];
    }
    __syncthreads();

    {
        float acc = g_b1[t];
        #pragma unroll 16
        for (int k = 0; k < 64; ++k) acc += hg[k]*g_w1[k*256 + t];
        h1_out[bh*256 + t] = 0.5f*acc*(1.0f + erff(acc*0.70710678118654752f));
    }
    if (t < 64) {
        float acc = w_b1[t];
        #pragma unroll 16
        for (int k = 0; k < 64; ++k) acc += wh[k]*w_w1[k*64 + t];
        w1o[t] = 0.5f*acc*(1.0f + erff(acc*0.70710678118654752f));
    }
    __syncthreads();

    if (t < 64) {
        float acc = w_b2[t];
        #pragma unroll 16
        for (int k = 0; k < 64; ++k) acc += w1o[k]*w_w2[k*64 + t];
        wscale[bh*64 + t] = 1.0f + 1.0f/(1.0f + expf(-acc));
    }
}

// ---------------- gates part B v4 ----------------
__global__ __launch_bounds__(256) void k_gate_g(const float* __restrict__ h1_ws,
                                                const float* __restrict__ g_w2,
                                                const float* __restrict__ g_b2,
                                                const float* __restrict__ mod_bias,
                                                float* __restrict__ G) {
    int bh = blockIdx.y;
    int t = threadIdx.x;
    int w = t >> 6, l = t & 63;
    int f = blockIdx.x*64 + l;
    int fc = f < NF ? f : NF-1;
    __shared__ float h1s[256];
    __shared__ float rre[4][64], rim[4][64];
    h1s[t] = h1_ws[bh*256 + t];
    __syncthreads();

    float re = 0.f, im = 0.f;
    const float* gw = g_w2 + (size_t)(w*64)*2050;
    const float* h1p = h1s + w*64;
    #pragma unroll 8
    for (int k = 0; k < 64; ++k) {
        float hv = h1p[k];
        re += hv * gw[(size_t)k*2050 + fc];
        im += hv * gw[(size_t)k*2050 + NF + fc];
    }
    rre[w][l] = re; rim[w][l] = im;
    __syncthreads();
    if (w == 0 && f < NF) {
        float rr = rre[0][l]+rre[1][l]+rre[2][l]+rre[3][l] + g_b2[f];
        float ii = rim[0][l]+rim[1][l]+rim[2][l]+rim[3][l] + g_b2[NF+f];
        float mag = sqrtf(rr*rr + ii*ii);
        float mult = fmaxf(mag + mod_bias[f], 0.f) / (mag + 1e-6f);
        float s = mult * (1.0f/2048.0f);
        float gr = s*rr, gi = s*ii;
        if (f == 0 || f == 1024) gi = 0.f;
        float* Gb = G + (size_t)bh*4096;
        Gb[2*f]   = gr;
        Gb[2*f+1] = gi;
        if (f >= 1 && f <= 1023) {
            Gb[2*(2048-f)]   = gr;
            Gb[2*(2048-f)+1] = -gi;
        }
    }
}

// ---------------- weight transpose + fp16 convert ----------------
__global__ void k_wsplit(const float* __restrict__ Wv, const float* __restrict__ Wo,
                         u16* __restrict__ WvH, u16* __restrict__ WoH) {
    const float* W = blockIdx.z ? Wo : Wv;
    u16* TH = blockIdx.z ? WoH : WvH;
    __shared__ float tile[32][33];
    int t = threadIdx.x;
    int n0 = blockIdx.x*32, k0 = blockIdx.y*32;
    #pragma unroll
    for (int i = 0; i < 4; ++i) {
        int k = (t >> 5) + 8*i;
        tile[k][t & 31] = W[(size_t)(k0 + k)*D_ + n0 + (t & 31)];
    }
    __syncthreads();
    int n = t >> 3, kc = (t & 7)*4;
    ushort4 h;
    h.x = f2h(tile[kc+0][n]);
    h.y = f2h(tile[kc+1][n]);
    h.z = f2h(tile[kc+2][n]);
    h.w = f2h(tile[kc+3][n]);
    *(ushort4*)&TH[(size_t)(n0 + n)*D_ + k0 + kc] = h;
}

// ---------------- fp16 MFMA GEMM, 64x128 tile, plain 2-barrier (proven floor) ----------
// LDS linear; chunk = 16B; XOR-swizzled source + reads (rule #21).
// EPI==0: fp16 pairs into packed z16; EPI==1: fp32 to C.
template<int EPI>
__global__ __launch_bounds__(256) void k_mfma_gemm(const u16* __restrict__ Ahi,
                                                   const u16* __restrict__ Bhi,
                                                   float* __restrict__ C) {
    __shared__ u16 AsH[64*64], BsH[128*64];   // 24 KiB
    int t = threadIdx.x;
    size_t rowBase = (size_t)blockIdx.x * 64;
    int colBase = blockIdx.y * 128;
    f32x4 acc[2][4] = {};
    int lane = t & 63;
    int wr = (t >> 7) & 1, wc = (t >> 6) & 1;
    int lr = lane & 15, lq = lane >> 4;

    for (int k0 = 0; k0 < 1024; k0 += 64) {
        #pragma unroll
        for (int i = 0; i < 2; ++i) {
            int c = t + i*256;
            int r = c >> 3, cs = c & 7;
            int ko = (cs ^ (r & 7)) << 3;
            __builtin_amdgcn_global_load_lds(
                (const __attribute__((address_space(1))) void*)(Ahi + (rowBase + (size_t)r)*D_ + k0 + ko),
                (__attribute__((address_space(3))) void*)(AsH + c*8), 16, 0, 0);
        }
        #pragma unroll
        for (int i = 0; i < 4; ++i) {
            int c = t + i*256;
            int r = c >> 3, cs = c & 7;
            int ko = (cs ^ (r & 7)) << 3;
            __builtin_amdgcn_global_load_lds(
                (const __attribute__((address_space(1))) void*)(Bhi + ((size_t)colBase + r)*D_ + k0 + ko),
                (__attribute__((address_space(3))) void*)(BsH + c*8), 16, 0, 0);
        }
        __syncthreads();
        #pragma unroll
        for (int ks = 0; ks < 2; ++ks) {
            f16x8 ah[2], bh[4];
            #pragma unroll
            for (int m = 0; m < 2; ++m) {
                int row = wr*32 + m*16 + lr;
                int ch = (ks*4 + lq) ^ (row & 7);
                ah[m] = *(const f16x8*)(AsH + row*64 + ch*8);
            }
            #pragma unroll
            for (int n = 0; n < 4; ++n) {
                int row = wc*64 + n*16 + lr;
                int ch = (ks*4 + lq) ^ (row & 7);
                bh[n] = *(const f16x8*)(BsH + row*64 + ch*8);
            }
            #pragma unroll
            for (int m = 0; m < 2; ++m) {
                #pragma unroll
                for (int n = 0; n < 4; ++n) {
                    acc[m][n] = __builtin_amdgcn_mfma_f32_16x16x32_f16(ah[m], bh[n], acc[m][n], 0, 0, 0);
                }
            }
        }
        __syncthreads();
    }

    int cr = lq * 4, cc = lane & 15;
    if (EPI == 0) {
        u16* Z = (u16*)C;
        #pragma unroll
        for (int m = 0; m < 2; ++m) {
            #pragma unroll
            for (int n = 0; n < 4; ++n) {
                int d = colBase + wc*64 + n*16 + cc;
                int hh = d >> 6, pr = (d >> 1) & 31, p = d & 1;
                #pragma unroll
                for (int r = 0; r < 4; ++r) {
                    size_t gr = rowBase + wr*32 + m*16 + cr + r;
                    int b = (int)(gr >> 11), l = (int)(gr & 2047);
                    Z[(((size_t)((b*16 + hh)*32 + pr))*L_ + l)*2 + p] = f2h(acc[m][n][r]);
                }
            }
        }
    } else {
        #pragma unroll
        for (int m = 0; m < 2; ++m) {
            #pragma unroll
            for (int n = 0; n < 4; ++n) {
                int d = colBase + wc*64 + n*16 + cc;
                #pragma unroll
                for (int r = 0; r < 4; ++r) {
                    size_t gr = rowBase + wr*32 + m*16 + cr + r;
                    C[gr*D_ + d] = acc[m][n][r];
                }
            }
        }
    }
}

// ---------------- register radix-8 FFT-2048 (fp16 I/O, fp32 compute) ----------------
__device__ __forceinline__ float2 cmulp(float2 a, float2 b) {
    return make_float2(a.x*b.x - a.y*b.y, a.x*b.y + a.y*b.x);
}
__device__ __forceinline__ float2 cadd(float2 a, float2 b){ return make_float2(a.x+b.x, a.y+b.y); }
__device__ __forceinline__ float2 csub(float2 a, float2 b){ return make_float2(a.x-b.x, a.y-b.y); }
__device__ __forceinline__ float2 cnegi(float2 a){ return make_float2(a.y, -a.x); }
__device__ __forceinline__ float2 cposi(float2 a){ return make_float2(-a.y, a.x); }

#define RH_ 0.70710678118654752f

__device__ __forceinline__ void fwd3(float2* e, float2 w1) {
    float2 tA1 = make_float2((w1.x + w1.y)*RH_, (w1.y - w1.x)*RH_);
    float2 tA2 = cnegi(w1);
    float2 tA3 = make_float2((w1.y - w1.x)*RH_, -(w1.x + w1.y)*RH_);
    float2 a, b, d;
    a=e[0]; b=e[4]; e[0]=cadd(a,b); d=csub(a,b); e[4]=cmulp(d, w1);
    a=e[1]; b=e[5]; e[1]=cadd(a,b); d=csub(a,b); e[5]=cmulp(d, tA1);
    a=e[2]; b=e[6]; e[2]=cadd(a,b); d=csub(a,b); e[6]=cmulp(d, tA2);
    a=e[3]; b=e[7]; e[3]=cadd(a,b); d=csub(a,b); e[7]=cmulp(d, tA3);
    float2 w2 = cmulp(w1,w1); float2 w2n = cnegi(w2);
    a=e[0]; b=e[2]; e[0]=cadd(a,b); d=csub(a,b); e[2]=cmulp(d, w2);
    a=e[1]; b=e[3]; e[1]=cadd(a,b); d=csub(a,b); e[3]=cmulp(d, w2n);
    a=e[4]; b=e[6]; e[4]=cadd(a,b); d=csub(a,b); e[6]=cmulp(d, w2);
    a=e[5]; b=e[7]; e[5]=cadd(a,b); d=csub(a,b); e[7]=cmulp(d, w2n);
    float2 w4 = cmulp(w2,w2);
    a=e[0]; b=e[1]; e[0]=cadd(a,b); d=csub(a,b); e[1]=cmulp(d, w4);
    a=e[2]; b=e[3]; e[2]=cadd(a,b); d=csub(a,b); e[3]=cmulp(d, w4);
    a=e[4]; b=e[5]; e[4]=cadd(a,b); d=csub(a,b); e[5]=cmulp(d, w4);
    a=e[6]; b=e[7]; e[6]=cadd(a,b); d=csub(a,b); e[7]=cmulp(d, w4);
}

__device__ __forceinline__ void inv3(float2* e, float2 b1) {
    float2 b2 = cmulp(b1,b1), b4 = cmulp(b2,b2);
    float2 a, bb;
    bb=cmulp(e[1],b4); a=e[0]; e[0]=cadd(a,bb); e[1]=csub(a,bb);
    bb=cmulp(e[3],b4); a=e[2]; e[2]=cadd(a,bb); e[3]=csub(a,bb);
    bb=cmulp(e[5],b4); a=e[4]; e[4]=cadd(a,bb); e[5]=csub(a,bb);
    bb=cmulp(e[7],b4); a=e[6]; e[6]=cadd(a,bb); e[7]=csub(a,bb);
    float2 b2i = cposi(b2);
    bb=cmulp(e[2],b2);  a=e[0]; e[0]=cadd(a,bb); e[2]=csub(a,bb);
    bb=cmulp(e[3],b2i); a=e[1]; e[1]=cadd(a,bb); e[3]=csub(a,bb);
    bb=cmulp(e[6],b2);  a=e[4]; e[4]=cadd(a,bb); e[6]=csub(a,bb);
    bb=cmulp(e[7],b2i); a=e[5]; e[5]=cadd(a,bb); e[7]=csub(a,bb);
    float2 tB1 = make_float2((b1.x - b1.y)*RH_, (b1.x + b1.y)*RH_);
    float2 tB2 = cposi(b1);
    float2 tB3 = make_float2(-(b1.x + b1.y)*RH_, (b1.x - b1.y)*RH_);
    bb=cmulp(e[4],b1);  a=e[0]; e[0]=cadd(a,bb); e[4]=csub(a,bb);
    bb=cmulp(e[5],tB1); a=e[1]; e[1]=cadd(a,bb); e[5]=csub(a,bb);
    bb=cmulp(e[6],tB2); a=e[2]; e[2]=cadd(a,bb); e[6]=csub(a,bb);
    bb=cmulp(e[7],tB3); a=e[3]; e[3]=cadd(a,bb); e[7]=csub(a,bb);
}

__device__ __forceinline__ void inv2(float2* e, float2 b1) {
    float2 b2 = cmulp(b1,b1);
    float2 a, bb;
    bb=cmulp(e[1],b2); a=e[0]; e[0]=cadd(a,bb); e[1]=csub(a,bb);
    bb=cmulp(e[3],b2); a=e[2]; e[2]=cadd(a,bb); e[3]=csub(a,bb);
    float2 b1i = cposi(b1);
    bb=cmulp(e[2],b1);  a=e[0]; e[0]=cadd(a,bb); e[2]=csub(a,bb);
    bb=cmulp(e[3],b1i); a=e[1]; e[1]=cadd(a,bb); e[3]=csub(a,bb);
}

#define PIDX(i) ((i) + ((i)>>5))

__global__ __launch_bounds__(256, 4) void k_fft(unsigned* __restrict__ z16,
                                                const float* __restrict__ G,
                                                const float* __restrict__ wscale) {
    __shared__ float2 dsh[2112];
    int t = threadIdx.x;
    int row = blockIdx.x;
    int bh = row >> 5, jp = row & 31;
    unsigned* zr = z16 + (size_t)row * L_;
    const float PIO = 3.14159265358979323846f;

    float2 e[8];
    #pragma unroll
    for (int j = 0; j < 8; ++j) {
        unsigned u = zr[t + 256*j];
        e[j] = make_float2(h2fu(u & 0xffffu), h2fu(u >> 16));
    }
    {
        float s_, c_; __sincosf(-(PIO/1024.f)*(float)t, &s_, &c_);
        fwd3(e, make_float2(c_, s_));
    }
    #pragma unroll
    for (int j = 0; j < 8; ++j) { int i = t + 256*j; dsh[PIDX(i)] = e[j]; }
    __syncthreads();

    {
        int q = t >> 5, r = t & 31, base = q*256 + r;
        #pragma unroll
        for (int j = 0; j < 8; ++j) { int i = base + 32*j; e[j] = dsh[PIDX(i)]; }
        float s_, c_; __sincosf(-(PIO/128.f)*(float)r, &s_, &c_);
        fwd3(e, make_float2(c_, s_));
        #pragma unroll
        for (int j = 0; j < 8; ++j) { int i = base + 32*j; dsh[PIDX(i)] = e[j]; }
    }
    __syncthreads();

    {
        int q = t >> 2, r = t & 3, base = q*32 + r;
        #pragma unroll
        for (int j = 0; j < 8; ++j) { int i = base + 4*j; e[j] = dsh[PIDX(i)]; }
        float s_, c_; __sincosf(-(PIO/16.f)*(float)r, &s_, &c_);
        fwd3(e, make_float2(c_, s_));
        #pragma unroll
        for (int j = 0; j < 8; ++j) { int i = base + 4*j; dsh[PIDX(i)] = e[j]; }
    }
    __syncthreads();

    {
        #pragma unroll
        for (int u = 0; u < 8; ++u) { int i = 8*t + u; e[u] = dsh[PIDX(i)]; }
        float2 a, b, d;
        a=e[0]; b=e[2]; e[0]=cadd(a,b); e[2]=csub(a,b);
        a=e[1]; b=e[3]; e[1]=cadd(a,b); d=csub(a,b); e[3]=cnegi(d);
        a=e[4]; b=e[6]; e[4]=cadd(a,b); e[6]=csub(a,b);
        a=e[5]; b=e[7]; e[5]=cadd(a,b); d=csub(a,b); e[7]=cnegi(d);
        a=e[0]; b=e[1]; e[0]=cadd(a,b); e[1]=csub(a,b);
        a=e[2]; b=e[3]; e[2]=cadd(a,b); e[3]=csub(a,b);
        a=e[4]; b=e[5]; e[4]=cadd(a,b); e[5]=csub(a,b);
        a=e[6]; b=e[7]; e[6]=cadd(a,b); e[7]=csub(a,b);
        int flo = (int)(__brev((unsigned)t) >> 24);
        const float2* Gb = (const float2*)(G + (size_t)bh*4096);
        e[0] = cmulp(e[0], Gb[flo + 256*0]);
        e[1] = cmulp(e[1], Gb[flo + 256*4]);
        e[2] = cmulp(e[2], Gb[flo + 256*2]);
        e[3] = cmulp(e[3], Gb[flo + 256*6]);
        e[4] = cmulp(e[4], Gb[flo + 256*1]);
        e[5] = cmulp(e[5], Gb[flo + 256*5]);
        e[6] = cmulp(e[6], Gb[flo + 256*3]);
        e[7] = cmulp(e[7], Gb[flo + 256*7]);
        inv3(e, make_float2(1.f, 0.f));
        #pragma unroll
        for (int u = 0; u < 8; ++u) { int i = 8*t + u; dsh[PIDX(i)] = e[u]; }
    }
    __syncthreads();

    {
        int q = t >> 3, r = t & 7, base = q*64 + r;
        #pragma unroll
        for (int j = 0; j < 8; ++j) { int i = base + 8*j; e[j] = dsh[PIDX(i)]; }
        float s_, c_; __sincosf((PIO/32.f)*(float)r, &s_, &c_);
        inv3(e, make_float2(c_, s_));
        #pragma unroll
        for (int j = 0; j < 8; ++j) { int i = base + 8*j; dsh[PIDX(i)] = e[j]; }
    }
    __syncthreads();

    {
        int q = t >> 6, r = t & 63, base = q*512 + r;
        #pragma unroll
        for (int j = 0; j < 8; ++j) { int i = base + 64*j; e[j] = dsh[PIDX(i)]; }
        float s_, c_; __sincosf((PIO/256.f)*(float)r, &s_, &c_);
        inv3(e, make_float2(c_, s_));
        #pragma unroll
        for (int j = 0; j < 8; ++j) { int i = base + 64*j; dsh[PIDX(i)] = e[j]; }
    }
    __syncthreads();

    {
        #pragma unroll
        for (int j = 0; j < 4; ++j) { int i = t + 512*j; e[j] = dsh[PIDX(i)]; }
        #pragma unroll
        for (int j = 0; j < 4; ++j) { int i = t + 256 + 512*j; e[4+j] = dsh[PIDX(i)]; }
        float s_, c_; __sincosf((PIO/1024.f)*(float)t, &s_, &c_);
        float2 b1 = make_float2(c_, s_);
        inv2(e, b1);
        float2 b1b = make_float2((b1.x - b1.y)*RH_, (b1.x + b1.y)*RH_);
        inv2(e+4, b1b);
        float sc0 = wscale[bh*64 + 2*jp];
        float sc1 = wscale[bh*64 + 2*jp + 1];
        #pragma unroll
        for (int j = 0; j < 4; ++j) {
            unsigned lo = f2h(e[j].x*sc0), hi = f2h(e[j].y*sc1);
            zr[t + 512*j] = lo | (hi << 16);
        }
        #pragma unroll
        for (int j = 0; j < 4; ++j) {
            unsigned lo = f2h(e[4+j].x*sc0), hi = f2h(e[4+j].y*sc1);
            zr[t + 256 + 512*j] = lo | (hi << 16);
        }
    }
}

// ---------------- z16 (fp16 pairs) -> vmix [m][d] fp16 transpose ----------------
__global__ void k_vsplit(const unsigned* __restrict__ z16, u16* __restrict__ vhi) {
    int t = threadIdx.x;
    int lt = blockIdx.x, h = blockIdx.y, b = blockIdx.z;
    int l0 = lt*64;
    __shared__ unsigned tile[64][33];
    const unsigned* zb = z16 + (size_t)(b*16 + h)*32*L_;
    int pr = t >> 3, lg = t & 7;
    #pragma unroll
    for (int i = 0; i < 8; ++i) {
        int l = lg*8 + i;
        tile[l][pr] = zb[(size_t)pr*L_ + l0 + l];
    }
    __syncthreads();
    int l = t >> 2, q0 = (t & 3) * 8;
    u16x8 o0, o1;
    #pragma unroll
    for (int i = 0; i < 4; ++i) {
        unsigned u = tile[l][q0+i];
        o0[2*i]   = (u16)(u & 0xffffu);
        o0[2*i+1] = (u16)(u >> 16);
    }
    #pragma unroll
    for (int i = 0; i < 4; ++i) {
        unsigned u = tile[l][q0+4+i];
        o1[2*i]   = (u16)(u & 0xffffu);
        o1[2*i+1] = (u16)(u >> 16);
    }
    size_t base = ((size_t)(b*L_) + l0 + l)*D_ + h*64 + q0*2;
    *(u16x8*)&vhi[base]   = o0;
    *(u16x8*)&vhi[base+8] = o1;
}

extern "C" void kernel_launch(void* const* d_in, const int* in_sizes, int n_in,
                              void* d_out, int out_size, void* d_ws, size_t ws_size,
                              hipStream_t stream) {
    const float* x      = (const float*)d_in[0];
    const float* Wq     = (const float*)d_in[1];
    const float* Wv     = (const float*)d_in[2];
    const float* Wo     = (const float*)d_in[3];
    const float* g_ln_w = (const float*)d_in[4];
    const float* g_ln_b = (const float*)d_in[5];
    const float* g_w1   = (const float*)d_in[6];
    const float* g_b1   = (const float*)d_in[7];
    const float* g_w2   = (const float*)d_in[8];
    const float* g_b2   = (const float*)d_in[9];
    const float* mod_b  = (const float*)d_in[10];
    const float* w_ln_w = (const float*)d_in[11];
    const float* w_ln_b = (const float*)d_in[12];
    const float* w_w1   = (const float*)d_in[13];
    const float* w_b1   = (const float*)d_in[14];
    const float* w_w2   = (const float*)d_in[15];
    const float* w_b2   = (const float*)d_in[16];

    float* ws   = (float*)d_ws;
    unsigned* z16 = (unsigned*)(ws + Z_OFF);
    float* G    = ws + G_OFF;
    float* wsc  = ws + WSC_OFF;
    float* xbar = ws + XB_OFF;
    float* part = ws + PART_OFF;
    float* h1ws = ws + H1_OFF;
    float* qpart= ws + QP_OFF;
    u16* xhi = (u16*)(ws + XHI_OFF);
    u16* WvH = (u16*)(ws + WVH_OFF);
    u16* WoH = (u16*)(ws + WOH_OFF);
    u16* vhi = xhi;
    float* outp = (float*)d_out;

    dim3 gx(4, 32, 4);
    k_xbar1h<<<gx, 256, 0, stream>>>(x, part, xhi);
    k_xbar2<<<16, 256, 0, stream>>>(part, xbar);
    dim3 gq(4, 4, 8);
    k_qmean1<<<gq, 256, 0, stream>>>(xbar, Wq, qpart);
    k_gates_a<<<64, 256, 0, stream>>>(qpart, g_ln_w, g_ln_b, g_w1, g_b1,
                                      w_ln_w, w_ln_b, w_w1, w_b1, w_w2, w_b2,
                                      h1ws, wsc);
    dim3 ggate(17, 64);
    k_gate_g<<<ggate, 256, 0, stream>>>(h1ws, g_w2, g_b2, mod_b, G);
    dim3 gw(32, 32, 2);
    k_wsplit<<<gw, 256, 0, stream>>>(Wv, Wo, WvH, WoH);

    dim3 gg(128, 8);
    k_mfma_gemm<0><<<gg, 256, 0, stream>>>(xhi, WvH, (float*)z16);
    k_fft<<<2048, 256, 0, stream>>>(z16, G, wsc);
    dim3 gv(32, 16, 4);
    k_vsplit<<<gv, 256, 0, stream>>>(z16, vhi);
    k_mfma_gemm<1><<<gg, 256, 0, stream>>>(vhi, WoH, outp);
}